// Round 5
// baseline (63.375 us; speedup 1.0000x reference)
//
#include <hip/hip_runtime.h>

// AdditiveAttention: B=2,H=8,Q=512,K=512,D=64
//   scores[b,h,q,k] = V_b + sum_d V_w[d]*tanh(q_proj[q,d] + k_proj[k,d])
//
// tanh(x) = 1 - 2/(1+e^{2x});  e^{2(qp+kp)} = eq*gk,
//   eq = exp2(C*qp), gk = exp2(C*kp), C = 2*log2(e)
// term_d = Vw[d]/(1 + eq[d]*gk[d]);  score = (Vb + sumVw) - 2*sum_d term_d
// Pairwise rcp: v0/A + v1/B = (v0*B + v1*A) * rcp(A*B),  A = fma(eq,g,1).
// => per d-pair: 2 fma + 2 mul + 2 fma + 1 v_rcp = 6 VALU + 1 trans / 2 elems.

#define BHX 16
#define SEQ 512
#define DDIM 64

typedef float f4 __attribute__((ext_vector_type(4)));

// Both projections in one launch. blocks 0..511: query->eq, 512..1023: keys->gk.
__global__ __launch_bounds__(256) void proj_kernel(
    const float* __restrict__ query, const float* __restrict__ keys,
    const float* __restrict__ Wa_w,  const float* __restrict__ Wa_b,
    const float* __restrict__ Ua_w,  const float* __restrict__ Ua_b,
    float* __restrict__ eq, float* __restrict__ gk)
{
  const int t = threadIdx.x, lane = t & 63, wave = t >> 6;
  const bool is_k = blockIdx.x >= 512;
  const float* __restrict__ X  = is_k ? keys : query;
  const float* __restrict__ W  = is_k ? Ua_w : Wa_w;
  const float* __restrict__ Bv = is_k ? Ua_b : Wa_b;
  float* __restrict__ out      = is_k ? gk : eq;
  const int row0 = (blockIdx.x & 511) * 16;

  float w[64];
  const float4* W4 = (const float4*)(W + lane * DDIM);
#pragma unroll
  for (int i = 0; i < 16; ++i) {
    float4 v = W4[i];
    w[4*i] = v.x; w[4*i+1] = v.y; w[4*i+2] = v.z; w[4*i+3] = v.w;
  }
#pragma unroll
  for (int i = 0; i < 16; ++i)
    asm volatile("" : "+v"(w[4*i]), "+v"(w[4*i+1]), "+v"(w[4*i+2]), "+v"(w[4*i+3]));

  const float C = 2.885390081777926815f;          // 2*log2(e)
  const float b = Bv[lane];

#pragma unroll 1
  for (int i = 0; i < 4; ++i) {
    const int r   = row0 + wave * 4 + i;
    const int off = __builtin_amdgcn_readfirstlane(r * DDIM);
    const float* xr = X + off;                    // wave-uniform -> s_load
    float a0 = 0, a1 = 0, a2 = 0, a3 = 0;
#pragma unroll
    for (int e = 0; e < 64; e += 4) {
      a0 = __builtin_fmaf(xr[e],     w[e],     a0);
      a1 = __builtin_fmaf(xr[e + 1], w[e + 1], a1);
      a2 = __builtin_fmaf(xr[e + 2], w[e + 2], a2);
      a3 = __builtin_fmaf(xr[e + 3], w[e + 3], a3);
    }
    float p = ((a0 + a1) + (a2 + a3)) + b;
    out[(size_t)r * DDIM + lane] = __builtin_amdgcn_exp2f(C * p);
  }
}

// Grid (8,8,16)=1024 blocks, 256 threads. Block = 64 k (lanes) x 64 q
// (wave w: q rows w*16..w*16+15). Lane's k-row g[0..63] lives in VGPRs,
// loaded via inline-asm global_load (un-sinkable, un-rematerializable).
// q values arrive per chunk as wave-uniform s_loads; Vw via s_loads.
// No LDS anywhere.
__global__ __launch_bounds__(256)
__attribute__((amdgpu_waves_per_eu(4, 4)))
void score_kernel(
    const float* __restrict__ eq,   // [BH*512][64]
    const float* __restrict__ gk,   // [BH*512][64]
    const float* __restrict__ Vw,   // [64]
    const float* __restrict__ Vb,   // [1]
    float* __restrict__ out)        // [BH,512,512]
{
  const int bh   = blockIdx.z;
  const int q0   = blockIdx.y * 64;
  const int k0   = blockIdx.x * 64;
  const int lane = threadIdx.x & 63;
  const int wave = threadIdx.x >> 6;

  // ---- load this lane's 64 g values via asm (pinned in VGPRs) ----
  f4 G[16];
  {
    const float* ga = gk + (size_t)(bh * SEQ + k0 + lane) * DDIM;
    asm volatile("global_load_dwordx4 %0, %1, off offset:0"   : "=v"(G[0])  : "v"(ga));
    asm volatile("global_load_dwordx4 %0, %1, off offset:16"  : "=v"(G[1])  : "v"(ga));
    asm volatile("global_load_dwordx4 %0, %1, off offset:32"  : "=v"(G[2])  : "v"(ga));
    asm volatile("global_load_dwordx4 %0, %1, off offset:48"  : "=v"(G[3])  : "v"(ga));
    asm volatile("global_load_dwordx4 %0, %1, off offset:64"  : "=v"(G[4])  : "v"(ga));
    asm volatile("global_load_dwordx4 %0, %1, off offset:80"  : "=v"(G[5])  : "v"(ga));
    asm volatile("global_load_dwordx4 %0, %1, off offset:96"  : "=v"(G[6])  : "v"(ga));
    asm volatile("global_load_dwordx4 %0, %1, off offset:112" : "=v"(G[7])  : "v"(ga));
    asm volatile("global_load_dwordx4 %0, %1, off offset:128" : "=v"(G[8])  : "v"(ga));
    asm volatile("global_load_dwordx4 %0, %1, off offset:144" : "=v"(G[9])  : "v"(ga));
    asm volatile("global_load_dwordx4 %0, %1, off offset:160" : "=v"(G[10]) : "v"(ga));
    asm volatile("global_load_dwordx4 %0, %1, off offset:176" : "=v"(G[11]) : "v"(ga));
    asm volatile("global_load_dwordx4 %0, %1, off offset:192" : "=v"(G[12]) : "v"(ga));
    asm volatile("global_load_dwordx4 %0, %1, off offset:208" : "=v"(G[13]) : "v"(ga));
    asm volatile("global_load_dwordx4 %0, %1, off offset:224" : "=v"(G[14]) : "v"(ga));
    asm volatile("global_load_dwordx4 %0, %1, off offset:240" : "=v"(G[15]) : "v"(ga));
    asm volatile("s_waitcnt vmcnt(0)"
                 : "+v"(G[0]), "+v"(G[1]), "+v"(G[2]),  "+v"(G[3]),
                   "+v"(G[4]), "+v"(G[5]), "+v"(G[6]),  "+v"(G[7]),
                   "+v"(G[8]), "+v"(G[9]), "+v"(G[10]), "+v"(G[11]),
                   "+v"(G[12]),"+v"(G[13]),"+v"(G[14]), "+v"(G[15])
                 :: "memory");
  }

  // acc0 = V_b + sum_d V_w[d]  (uniform, scalar pipe)
  float acc0 = Vb[0];
#pragma unroll
  for (int d = 0; d < 64; ++d) acc0 += Vw[d];

  const int qb = q0 + wave * 16;
  const int qbase = __builtin_amdgcn_readfirstlane((bh * SEQ + qb) * DDIM);

#pragma unroll 1
  for (int qi = 0; qi < 16; ++qi) {
    const float* qr = eq + qbase + qi * DDIM;   // wave-uniform -> s_load
    float a = 0.f;
#pragma unroll
    for (int c = 0; c < 4; ++c) {
#pragma unroll
      for (int p = 0; p < 8; p += 2) {          // 2 d-pairs per step
        // pair 0: d = c*16 + 2p
        {
          const int d = c * 16 + 2 * p;
          const float A = __builtin_fmaf(qr[d],     G[4*c + p/2][0], 1.0f);
          const float B = __builtin_fmaf(qr[d + 1], G[4*c + p/2][1], 1.0f);
          const float num = __builtin_fmaf(Vw[d + 1], A, Vw[d] * B);
          a = __builtin_fmaf(num, __builtin_amdgcn_rcpf(A * B), a);
        }
        // pair 1: d = c*16 + 2p + 2
        {
          const int d = c * 16 + 2 * p + 2;
          const float A = __builtin_fmaf(qr[d],     G[4*c + p/2][2], 1.0f);
          const float B = __builtin_fmaf(qr[d + 1], G[4*c + p/2][3], 1.0f);
          const float num = __builtin_fmaf(Vw[d + 1], A, Vw[d] * B);
          a = __builtin_fmaf(num, __builtin_amdgcn_rcpf(A * B), a);
        }
      }
    }
    out[(size_t)(bh * SEQ + qb + qi) * SEQ + k0 + lane] =
        __builtin_fmaf(-2.f, a, acc0);
  }
}

extern "C" void kernel_launch(void* const* d_in, const int* in_sizes, int n_in,
                              void* d_out, int out_size, void* d_ws, size_t ws_size,
                              hipStream_t stream) {
  const float* query = (const float*)d_in[0];  // [2,8,512,64]
  const float* keys  = (const float*)d_in[1];  // [2,8,512,64]
  const float* Wa_w  = (const float*)d_in[2];  // [64,64]
  const float* Wa_b  = (const float*)d_in[3];  // [64]
  const float* Ua_w  = (const float*)d_in[4];  // [64,64]
  const float* Ua_b  = (const float*)d_in[5];  // [64]
  const float* V_w   = (const float*)d_in[6];  // [64]
  const float* V_b   = (const float*)d_in[7];  // [1]
  float* out = (float*)d_out;

  const int R = BHX * SEQ;                 // 8192 rows each side
  float* eq = (float*)d_ws;                // 2 MiB
  float* gk = eq + (size_t)R * DDIM;       // 2 MiB

  proj_kernel<<<1024, 256, 0, stream>>>(query, keys, Wa_w, Wa_b,
                                        Ua_w, Ua_b, eq, gk);

  dim3 grid(SEQ / 64, SEQ / 64, BHX);      // 1024 blocks
  score_kernel<<<grid, 256, 0, stream>>>(eq, gk, V_w, V_b, out);
}

// Round 6
// 62.925 us; speedup vs baseline: 1.0072x; 1.0072x over previous
//
#include <hip/hip_runtime.h>

// AdditiveAttention: B=2,H=8,Q=512,K=512,D=64
//   scores[b,h,q,k] = V_b + sum_d V_w[d]*tanh(q_proj[q,d] + k_proj[k,d])
//
// tanh(x) = 1 - 2/(1+e^{2x});  e^{2(qp+kp)} = eq*gk,
//   eq = exp2(C*qp), gk = exp2(C*kp), C = 2*log2(e)
// term_d = Vw[d]/(1 + eq[d]*gk[d]);  score = (Vb + sumVw) - 2*sum_d term_d
// Pairwise rcp: v0/A + v1/B = (v0*B + v1*A)*rcp(A*B),  A = fma(eq,g,1).
//
// Hot-loop design (R5 lesson: per-qi wave-uniform s_load chains stall VALU):
//  - k-side: lane k's 64 g values pinned in VGPRs via inline-asm loads.
//  - q-side: lane l holds Q[qi] = eq[row qi][d=l]; eq[qi][d] is broadcast
//    with v_readlane (register op) -> ZERO memory ops in the hot loop.

#define BHX 16
#define SEQ 512
#define DDIM 64

typedef float f4 __attribute__((ext_vector_type(4)));

// Both projections in one launch. blocks 0..511: query->eq, 512..1023: keys->gk.
__global__ __launch_bounds__(256) void proj_kernel(
    const float* __restrict__ query, const float* __restrict__ keys,
    const float* __restrict__ Wa_w,  const float* __restrict__ Wa_b,
    const float* __restrict__ Ua_w,  const float* __restrict__ Ua_b,
    float* __restrict__ eq, float* __restrict__ gk)
{
  const int t = threadIdx.x, lane = t & 63, wave = t >> 6;
  const bool is_k = blockIdx.x >= 512;
  const float* __restrict__ X  = is_k ? keys : query;
  const float* __restrict__ W  = is_k ? Ua_w : Wa_w;
  const float* __restrict__ Bv = is_k ? Ua_b : Wa_b;
  float* __restrict__ out      = is_k ? gk : eq;
  const int row0 = (blockIdx.x & 511) * 16;

  float w[64];
  const float4* W4 = (const float4*)(W + lane * DDIM);
#pragma unroll
  for (int i = 0; i < 16; ++i) {
    float4 v = W4[i];
    w[4*i] = v.x; w[4*i+1] = v.y; w[4*i+2] = v.z; w[4*i+3] = v.w;
  }
#pragma unroll
  for (int i = 0; i < 16; ++i)
    asm volatile("" : "+v"(w[4*i]), "+v"(w[4*i+1]), "+v"(w[4*i+2]), "+v"(w[4*i+3]));

  const float C = 2.885390081777926815f;          // 2*log2(e)
  const float b = Bv[lane];

#pragma unroll 1
  for (int i = 0; i < 4; ++i) {
    const int r   = row0 + wave * 4 + i;
    const int off = __builtin_amdgcn_readfirstlane(r * DDIM);
    const float* xr = X + off;                    // wave-uniform -> s_load
    float a0 = 0, a1 = 0, a2 = 0, a3 = 0;
#pragma unroll
    for (int e = 0; e < 64; e += 4) {
      a0 = __builtin_fmaf(xr[e],     w[e],     a0);
      a1 = __builtin_fmaf(xr[e + 1], w[e + 1], a1);
      a2 = __builtin_fmaf(xr[e + 2], w[e + 2], a2);
      a3 = __builtin_fmaf(xr[e + 3], w[e + 3], a3);
    }
    float p = ((a0 + a1) + (a2 + a3)) + b;
    out[(size_t)r * DDIM + lane] = __builtin_amdgcn_exp2f(C * p);
  }
}

__device__ __forceinline__ float rdlane(float v, int l) {
  return __builtin_bit_cast(
      float, __builtin_amdgcn_readlane(__builtin_bit_cast(int, v), l));
}

// Grid (8,16,16)=2048 blocks, 256 threads. Block = 64 k (lanes) x 32 q
// (wave w: rows w*8..w*8+7). No memory ops in the hot loop.
__global__ __launch_bounds__(256)
__attribute__((amdgpu_waves_per_eu(4, 4)))
void score_kernel(
    const float* __restrict__ eq,   // [BH*512][64]
    const float* __restrict__ gk,   // [BH*512][64]
    const float* __restrict__ Vw,   // [64]
    const float* __restrict__ Vb,   // [1]
    float* __restrict__ out)        // [BH,512,512]
{
  const int bh   = blockIdx.z;
  const int q0   = blockIdx.y * 32;
  const int k0   = blockIdx.x * 64;
  const int lane = threadIdx.x & 63;
  const int wave = threadIdx.x >> 6;

  // ---- lane's k-row g[0..63], pinned via asm loads ----
  f4 G[16];
  {
    const float* ga = gk + (size_t)(bh * SEQ + k0 + lane) * DDIM;
    asm volatile("global_load_dwordx4 %0, %1, off offset:0"   : "=v"(G[0])  : "v"(ga));
    asm volatile("global_load_dwordx4 %0, %1, off offset:16"  : "=v"(G[1])  : "v"(ga));
    asm volatile("global_load_dwordx4 %0, %1, off offset:32"  : "=v"(G[2])  : "v"(ga));
    asm volatile("global_load_dwordx4 %0, %1, off offset:48"  : "=v"(G[3])  : "v"(ga));
    asm volatile("global_load_dwordx4 %0, %1, off offset:64"  : "=v"(G[4])  : "v"(ga));
    asm volatile("global_load_dwordx4 %0, %1, off offset:80"  : "=v"(G[5])  : "v"(ga));
    asm volatile("global_load_dwordx4 %0, %1, off offset:96"  : "=v"(G[6])  : "v"(ga));
    asm volatile("global_load_dwordx4 %0, %1, off offset:112" : "=v"(G[7])  : "v"(ga));
    asm volatile("global_load_dwordx4 %0, %1, off offset:128" : "=v"(G[8])  : "v"(ga));
    asm volatile("global_load_dwordx4 %0, %1, off offset:144" : "=v"(G[9])  : "v"(ga));
    asm volatile("global_load_dwordx4 %0, %1, off offset:160" : "=v"(G[10]) : "v"(ga));
    asm volatile("global_load_dwordx4 %0, %1, off offset:176" : "=v"(G[11]) : "v"(ga));
    asm volatile("global_load_dwordx4 %0, %1, off offset:192" : "=v"(G[12]) : "v"(ga));
    asm volatile("global_load_dwordx4 %0, %1, off offset:208" : "=v"(G[13]) : "v"(ga));
    asm volatile("global_load_dwordx4 %0, %1, off offset:224" : "=v"(G[14]) : "v"(ga));
    asm volatile("global_load_dwordx4 %0, %1, off offset:240" : "=v"(G[15]) : "v"(ga));
  }

  // ---- lane's slice of the wave's 8 q-rows: Q[qi] = eq[row qi][d=lane] ----
  float Q[8];
  {
    const float* qa = eq + (size_t)(bh * SEQ + q0 + wave * 8) * DDIM + lane;
#pragma unroll
    for (int qi = 0; qi < 8; ++qi) Q[qi] = qa[qi * DDIM];
  }

  // acc0 = V_b + sum_d V_w[d]  (uniform, scalar pipe)
  float acc0 = Vb[0];
#pragma unroll
  for (int d = 0; d < 64; ++d) acc0 += Vw[d];

  // Wait for both G (vmcnt via asm) and Q (compiler-tracked) and pin.
  asm volatile("s_waitcnt vmcnt(0)"
               : "+v"(G[0]), "+v"(G[1]), "+v"(G[2]),  "+v"(G[3]),
                 "+v"(G[4]), "+v"(G[5]), "+v"(G[6]),  "+v"(G[7]),
                 "+v"(G[8]), "+v"(G[9]), "+v"(G[10]), "+v"(G[11]),
                 "+v"(G[12]),"+v"(G[13]),"+v"(G[14]), "+v"(G[15])
               :: "memory");
  asm volatile("" : "+v"(Q[0]), "+v"(Q[1]), "+v"(Q[2]), "+v"(Q[3]),
                    "+v"(Q[4]), "+v"(Q[5]), "+v"(Q[6]), "+v"(Q[7]));

  const size_t obase = (size_t)(bh * SEQ + q0 + wave * 8) * SEQ + k0 + lane;

#pragma unroll
  for (int qi = 0; qi < 8; ++qi) {          // static -> no dynamic reg index
    float a0 = 0.f, a1 = 0.f;
#pragma unroll
    for (int p = 0; p < 32; ++p) {          // d-pairs, fully unrolled
      const int d = 2 * p;
      const float e0 = rdlane(Q[qi], d);       // v_readlane -> SGPR
      const float e1 = rdlane(Q[qi], d + 1);
      const float A  = __builtin_fmaf(e0, G[p >> 1][(d & 2)],     1.0f);
      const float B  = __builtin_fmaf(e1, G[p >> 1][(d & 2) + 1], 1.0f);
      const float num = __builtin_fmaf(Vw[d + 1], A, Vw[d] * B);
      const float r   = __builtin_amdgcn_rcpf(A * B);
      if (p & 1) a1 = __builtin_fmaf(num, r, a1);
      else       a0 = __builtin_fmaf(num, r, a0);
    }
    out[obase + (size_t)qi * SEQ] = __builtin_fmaf(-2.f, a0 + a1, acc0);
  }
}

extern "C" void kernel_launch(void* const* d_in, const int* in_sizes, int n_in,
                              void* d_out, int out_size, void* d_ws, size_t ws_size,
                              hipStream_t stream) {
  const float* query = (const float*)d_in[0];  // [2,8,512,64]
  const float* keys  = (const float*)d_in[1];  // [2,8,512,64]
  const float* Wa_w  = (const float*)d_in[2];  // [64,64]
  const float* Wa_b  = (const float*)d_in[3];  // [64]
  const float* Ua_w  = (const float*)d_in[4];  // [64,64]
  const float* Ua_b  = (const float*)d_in[5];  // [64]
  const float* V_w   = (const float*)d_in[6];  // [64]
  const float* V_b   = (const float*)d_in[7];  // [1]
  float* out = (float*)d_out;

  const int R = BHX * SEQ;                 // 8192 rows each side
  float* eq = (float*)d_ws;                // 2 MiB
  float* gk = eq + (size_t)R * DDIM;       // 2 MiB

  proj_kernel<<<1024, 256, 0, stream>>>(query, keys, Wa_w, Wa_b,
                                        Ua_w, Ua_b, eq, gk);

  dim3 grid(SEQ / 64, SEQ / 32, BHX);      // (8,16,16) = 2048 blocks
  score_kernel<<<grid, 256, 0, stream>>>(eq, gk, V_w, V_b, out);
}

// Round 7
// 48.450 us; speedup vs baseline: 1.3080x; 1.2987x over previous
//
#include <hip/hip_runtime.h>

// AdditiveAttention: B=2,H=8,Q=512,K=512,D=64
//   scores[b,h,q,k] = V_b + sum_d V_w[d]*tanh(q_proj[q,d] + k_proj[k,d])
//
// tanh(x) = 1 - 2/(1+e^{2x});  e^{2(qp+kp)} = eq*gk,
//   eq = exp2(C*qp), gk = exp2(C*kp), C = 2*log2(e)
// term_d = Vw[d]/A_d,  A_d = 1 + eq_d*gk_d
// score  = (Vb + sumVw) - 2*sum_d term_d
//
// 8-way fraction tree:  sum_{j=0..7} v_j/A_j = num/(A0..A7) -> ONE v_rcp per
// 8 elements (30 VALU + 1 rcp per 8).  R3-R6 all plateaued ~45-50us with
// 0.5 rcp/elem regardless of memory structure => probing trans-pipe cost.
//
// e-values (wave-uniform) come from an 8KB LDS q-tile via broadcast
// ds_read_b128 (LDS pipe, not VALU) -- replaces R6's 512 v_readlanes.

#define BHX 16
#define SEQ 512
#define DDIM 64
#define QT 32
#define KT 64

typedef float f4 __attribute__((ext_vector_type(4)));

// Both projections in one launch. blocks 0..511: query->eq, 512..1023: keys->gk.
__global__ __launch_bounds__(256) void proj_kernel(
    const float* __restrict__ query, const float* __restrict__ keys,
    const float* __restrict__ Wa_w,  const float* __restrict__ Wa_b,
    const float* __restrict__ Ua_w,  const float* __restrict__ Ua_b,
    float* __restrict__ eq, float* __restrict__ gk)
{
  const int t = threadIdx.x, lane = t & 63, wave = t >> 6;
  const bool is_k = blockIdx.x >= 512;
  const float* __restrict__ X  = is_k ? keys : query;
  const float* __restrict__ W  = is_k ? Ua_w : Wa_w;
  const float* __restrict__ Bv = is_k ? Ua_b : Wa_b;
  float* __restrict__ out      = is_k ? gk : eq;
  const int row0 = (blockIdx.x & 511) * 16;

  float w[64];
  const float4* W4 = (const float4*)(W + lane * DDIM);
#pragma unroll
  for (int i = 0; i < 16; ++i) {
    float4 v = W4[i];
    w[4*i] = v.x; w[4*i+1] = v.y; w[4*i+2] = v.z; w[4*i+3] = v.w;
  }
#pragma unroll
  for (int i = 0; i < 16; ++i)
    asm volatile("" : "+v"(w[4*i]), "+v"(w[4*i+1]), "+v"(w[4*i+2]), "+v"(w[4*i+3]));

  const float C = 2.885390081777926815f;          // 2*log2(e)
  const float b = Bv[lane];

#pragma unroll 1
  for (int i = 0; i < 4; ++i) {
    const int r   = row0 + wave * 4 + i;
    const int off = __builtin_amdgcn_readfirstlane(r * DDIM);
    const float* xr = X + off;                    // wave-uniform -> s_load
    float a0 = 0, a1 = 0, a2 = 0, a3 = 0;
#pragma unroll
    for (int e = 0; e < 64; e += 4) {
      a0 = __builtin_fmaf(xr[e],     w[e],     a0);
      a1 = __builtin_fmaf(xr[e + 1], w[e + 1], a1);
      a2 = __builtin_fmaf(xr[e + 2], w[e + 2], a2);
      a3 = __builtin_fmaf(xr[e + 3], w[e + 3], a3);
    }
    float p = ((a0 + a1) + (a2 + a3)) + b;
    out[(size_t)r * DDIM + lane] = __builtin_amdgcn_exp2f(C * p);
  }
}

// Grid (8,16,16)=2048 blocks, 256 threads. Block = 64 k (lanes) x 32 q
// (wave w: rows w*8..w*8+7).
__global__ __launch_bounds__(256)
__attribute__((amdgpu_waves_per_eu(3)))
void score_kernel(
    const float* __restrict__ eq,   // [BH*512][64]
    const float* __restrict__ gk,   // [BH*512][64]
    const float* __restrict__ Vw,   // [64]
    const float* __restrict__ Vb,   // [1]
    float* __restrict__ out)        // [BH,512,512]
{
  __shared__ float ql[QT * DDIM];   // 8 KB q-tile, read via uniform broadcast

  const int bh   = blockIdx.z;
  const int q0   = blockIdx.y * QT;
  const int k0   = blockIdx.x * KT;
  const int t    = threadIdx.x;
  const int lane = t & 63;
  const int wave = t >> 6;

  // ---- issue lane's k-row g[0..63] via asm (pinned in VGPRs) ----
  f4 G[16];
  {
    const float* ga = gk + (size_t)(bh * SEQ + k0 + lane) * DDIM;
    asm volatile("global_load_dwordx4 %0, %1, off offset:0"   : "=v"(G[0])  : "v"(ga));
    asm volatile("global_load_dwordx4 %0, %1, off offset:16"  : "=v"(G[1])  : "v"(ga));
    asm volatile("global_load_dwordx4 %0, %1, off offset:32"  : "=v"(G[2])  : "v"(ga));
    asm volatile("global_load_dwordx4 %0, %1, off offset:48"  : "=v"(G[3])  : "v"(ga));
    asm volatile("global_load_dwordx4 %0, %1, off offset:64"  : "=v"(G[4])  : "v"(ga));
    asm volatile("global_load_dwordx4 %0, %1, off offset:80"  : "=v"(G[5])  : "v"(ga));
    asm volatile("global_load_dwordx4 %0, %1, off offset:96"  : "=v"(G[6])  : "v"(ga));
    asm volatile("global_load_dwordx4 %0, %1, off offset:112" : "=v"(G[7])  : "v"(ga));
    asm volatile("global_load_dwordx4 %0, %1, off offset:128" : "=v"(G[8])  : "v"(ga));
    asm volatile("global_load_dwordx4 %0, %1, off offset:144" : "=v"(G[9])  : "v"(ga));
    asm volatile("global_load_dwordx4 %0, %1, off offset:160" : "=v"(G[10]) : "v"(ga));
    asm volatile("global_load_dwordx4 %0, %1, off offset:176" : "=v"(G[11]) : "v"(ga));
    asm volatile("global_load_dwordx4 %0, %1, off offset:192" : "=v"(G[12]) : "v"(ga));
    asm volatile("global_load_dwordx4 %0, %1, off offset:208" : "=v"(G[13]) : "v"(ga));
    asm volatile("global_load_dwordx4 %0, %1, off offset:224" : "=v"(G[14]) : "v"(ga));
    asm volatile("global_load_dwordx4 %0, %1, off offset:240" : "=v"(G[15]) : "v"(ga));
  }

  // ---- stage q-tile into LDS (coalesced, 2 float4 per thread) ----
  {
    const float4* src = (const float4*)(eq + (size_t)(bh * SEQ + q0) * DDIM);
    float4* dst = (float4*)ql;
    dst[t * 2]     = src[t * 2];
    dst[t * 2 + 1] = src[t * 2 + 1];
  }

  // acc0 = V_b + sum_d V_w[d]  (uniform, scalar pipe)
  float acc0 = Vb[0];
#pragma unroll
  for (int d = 0; d < 64; ++d) acc0 += Vw[d];

  __syncthreads();

  asm volatile("s_waitcnt vmcnt(0)"
               : "+v"(G[0]), "+v"(G[1]), "+v"(G[2]),  "+v"(G[3]),
                 "+v"(G[4]), "+v"(G[5]), "+v"(G[6]),  "+v"(G[7]),
                 "+v"(G[8]), "+v"(G[9]), "+v"(G[10]), "+v"(G[11]),
                 "+v"(G[12]),"+v"(G[13]),"+v"(G[14]), "+v"(G[15])
               :: "memory");

  const size_t obase = (size_t)(bh * SEQ + q0 + wave * 8) * SEQ + k0 + lane;

#pragma unroll 1
  for (int qi = 0; qi < 8; ++qi) {
    const float4* ev = (const float4*)(ql + (wave * 8 + qi) * DDIM);
    float accA = 0.f, accB = 0.f;
#pragma unroll
    for (int g = 0; g < 8; ++g) {           // 8 d's per group, 1 rcp each
      const float4 e0 = ev[2 * g];          // uniform ds_read_b128 (broadcast)
      const float4 e1 = ev[2 * g + 1];
      const float A0 = __builtin_fmaf(e0.x, G[2*g].x,     1.0f);
      const float A1 = __builtin_fmaf(e0.y, G[2*g].y,     1.0f);
      const float A2 = __builtin_fmaf(e0.z, G[2*g].z,     1.0f);
      const float A3 = __builtin_fmaf(e0.w, G[2*g].w,     1.0f);
      const float A4 = __builtin_fmaf(e1.x, G[2*g + 1].x, 1.0f);
      const float A5 = __builtin_fmaf(e1.y, G[2*g + 1].y, 1.0f);
      const float A6 = __builtin_fmaf(e1.z, G[2*g + 1].z, 1.0f);
      const float A7 = __builtin_fmaf(e1.w, G[2*g + 1].w, 1.0f);
      const int d = 8 * g;
      // pair fractions: n01/P01 = v0/A0 + v1/A1, etc.
      const float n01 = __builtin_fmaf(Vw[d + 1], A0, Vw[d]     * A1);
      const float n23 = __builtin_fmaf(Vw[d + 3], A2, Vw[d + 2] * A3);
      const float n45 = __builtin_fmaf(Vw[d + 5], A4, Vw[d + 4] * A5);
      const float n67 = __builtin_fmaf(Vw[d + 7], A6, Vw[d + 6] * A7);
      const float P01 = A0 * A1, P23 = A2 * A3, P45 = A4 * A5, P67 = A6 * A7;
      const float n0123 = __builtin_fmaf(n23, P01, n01 * P23);
      const float n4567 = __builtin_fmaf(n67, P45, n45 * P67);
      const float P0123 = P01 * P23, P4567 = P45 * P67;
      const float num   = __builtin_fmaf(n4567, P0123, n0123 * P4567);
      const float P     = P0123 * P4567;
      const float r     = __builtin_amdgcn_rcpf(P);
      if (g & 1) accB = __builtin_fmaf(num, r, accB);
      else       accA = __builtin_fmaf(num, r, accA);
    }
    out[obase + (size_t)qi * SEQ] = __builtin_fmaf(-2.f, accA + accB, acc0);
  }
}

extern "C" void kernel_launch(void* const* d_in, const int* in_sizes, int n_in,
                              void* d_out, int out_size, void* d_ws, size_t ws_size,
                              hipStream_t stream) {
  const float* query = (const float*)d_in[0];  // [2,8,512,64]
  const float* keys  = (const float*)d_in[1];  // [2,8,512,64]
  const float* Wa_w  = (const float*)d_in[2];  // [64,64]
  const float* Wa_b  = (const float*)d_in[3];  // [64]
  const float* Ua_w  = (const float*)d_in[4];  // [64,64]
  const float* Ua_b  = (const float*)d_in[5];  // [64]
  const float* V_w   = (const float*)d_in[6];  // [64]
  const float* V_b   = (const float*)d_in[7];  // [1]
  float* out = (float*)d_out;

  const int R = BHX * SEQ;                 // 8192 rows each side
  float* eq = (float*)d_ws;                // 2 MiB
  float* gk = eq + (size_t)R * DDIM;       // 2 MiB

  proj_kernel<<<1024, 256, 0, stream>>>(query, keys, Wa_w, Wa_b,
                                        Ua_w, Ua_b, eq, gk);

  dim3 grid(SEQ / KT, SEQ / QT, BHX);      // (8,16,16) = 2048 blocks
  score_kernel<<<grid, 256, 0, stream>>>(eq, gk, V_w, V_b, out);
}